// Round 2
// baseline (355.202 us; speedup 1.0000x reference)
//
#include <hip/hip_runtime.h>
#include <stdint.h>

#define BATCH 256
#define NNODE 512
#define INP   57
#define HIDD  512
#define OUTD  57

typedef __bf16 bf16x8 __attribute__((ext_vector_type(8)));
typedef float  f32x4  __attribute__((ext_vector_type(4)));

__device__ __forceinline__ float bf2f(unsigned short u){
  union { unsigned int i; float f; } c; c.i = ((unsigned int)u) << 16; return c.f;
}
__device__ __forceinline__ unsigned short f2bf(float f){
  union { float f; unsigned int i; } c; c.f = f;
  unsigned int u = c.i;
  return (unsigned short)((u + 0x7fffu + ((u >> 16) & 1u)) >> 16);
}

// Pre-pack Wh = W_ih[INP:, :] into MFMA B-fragment order (bf16).
// Fragment id = kt*32 + ntile; within fragment: lane holds B[k=kt*32+(lane>>4)*8+j][n=ntile*16+(lane&15)], j=0..7.
__global__ void pack_wh(const float* __restrict__ W_ih, unsigned short* __restrict__ Wp){
  int idx = blockIdx.x * 256 + threadIdx.x;      // 0..262143
  int j    =  idx        & 7;
  int lane = (idx >> 3)  & 63;
  int nt   = (idx >> 9)  & 31;
  int kt   =  idx >> 14;                         // 0..15
  int k = kt * 32 + (lane >> 4) * 8 + j;
  int n = nt * 16 + (lane & 15);
  Wp[idx] = f2bf(W_ih[(size_t)(INP + k) * HIDD + n]);
}

// One level-chunk: gather A = bf16(H[li]+H[ri]) for up to NMT*16 rows, GEMM vs Wp,
// tanh epilogue, scatter to Hb. NMT is compile-time so all acc indexing is static.
template<int NMT>
__device__ __forceinline__ void chunk_body(
    int m0, int Mcur, int w, int lane, int m16, int quad, int tid,
    unsigned short (*A_s)[HIDD + 8],
    const int* ord_s, const int* li_s, const int* ri_s, const int* val_s,
    const unsigned short* __restrict__ Wp,
    const float* __restrict__ W_ih, const float* __restrict__ b_ih,
    unsigned short* Hb)
{
  // ---- gather: A[r][:] = bf16( H[li] + H[ri] ); zero-pad rows >= Mcur ----
  {
    const int rr = tid >> 5;                 // 0..31 (row)
    const int cp = tid & 31;                 // 32 threads/row, 16 cols each
    if (rr < NMT * 16) {
      const unsigned short *pl = nullptr, *pr = nullptr;
      const bool live = rr < Mcur;
      if (live) {
        int node = ord_s[m0 + rr];
        int l = li_s[node], r = ri_s[node];
        pl = Hb + (size_t)(l < 0 ? NNODE : l) * HIDD;
        pr = Hb + (size_t)(r < 0 ? NNODE : r) * HIDD;
      }
      #pragma unroll
      for (int it = 0; it < 2; ++it) {
        const int c = cp * 16 + it * 8;
        uint4 res; res.x = 0; res.y = 0; res.z = 0; res.w = 0;
        if (live) {
          uint4 xa = *(const uint4*)(pl + c);
          uint4 xb = *(const uint4*)(pr + c);
          const unsigned short* ua = (const unsigned short*)&xa;
          const unsigned short* ub = (const unsigned short*)&xb;
          unsigned short* uo = (unsigned short*)&res;
          #pragma unroll
          for (int e = 0; e < 8; ++e)
            uo[e] = f2bf(bf2f(ua[e]) + bf2f(ub[e]));
        }
        *(uint4*)&A_s[rr][c] = res;
      }
    }
  }
  __syncthreads();

  // ---- MFMA: 16 waves; wave w owns n-tiles {2w, 2w+1}; NMT m-tiles ----
  f32x4 acc[NMT][2];
  #pragma unroll
  for (int mt = 0; mt < NMT; ++mt)
    #pragma unroll
    for (int nt = 0; nt < 2; ++nt)
      acc[mt][nt] = (f32x4){0.f, 0.f, 0.f, 0.f};

  const unsigned short* WpW = Wp + (size_t)(w * 2) * 512 + (size_t)lane * 8;
  #pragma unroll
  for (int kt = 0; kt < 16; ++kt) {
    const int kc = kt * 32 + quad * 8;
    bf16x8 a0 = *(const bf16x8*)&A_s[m16][kc];
    bf16x8 a1;
    if constexpr (NMT == 2) a1 = *(const bf16x8*)&A_s[16 + m16][kc];
    const unsigned short* bp = WpW + (size_t)kt * 16384;   // 32 fragments * 512 shorts
    #pragma unroll
    for (int nt = 0; nt < 2; ++nt) {
      bf16x8 bb = *(const bf16x8*)(bp + nt * 512);
      acc[0][nt] = __builtin_amdgcn_mfma_f32_16x16x32_bf16(a0, bb, acc[0][nt], 0, 0, 0);
      if constexpr (NMT == 2)
        acc[NMT - 1][nt] = __builtin_amdgcn_mfma_f32_16x16x32_bf16(a1, bb, acc[NMT - 1][nt], 0, 0, 0);
    }
  }

  // ---- epilogue: h = tanh(acc + Wx[val] + b_ih), store bf16 to H[b][node][:] ----
  // C/D layout: col = lane&15, row = quad*4 + reg   [m89-verified]
  #pragma unroll
  for (int nt = 0; nt < 2; ++nt) {
    const int col = (w * 2 + nt) * 16 + m16;
    const float bih = b_ih[col];
    #pragma unroll
    for (int mt = 0; mt < NMT; ++mt) {
      #pragma unroll
      for (int rg = 0; rg < 4; ++rg) {
        const int rowc = mt * 16 + quad * 4 + rg;
        if (rowc < Mcur) {
          const int node = ord_s[m0 + rowc];
          const float xp = W_ih[(size_t)val_s[node] * HIDD + col] + bih;
          const float v  = acc[mt][nt][rg] + xp;
          const float e  = __expf(2.0f * v);
          const float t  = 1.0f - __fdividef(2.0f, e + 1.0f);
          Hb[(size_t)node * HIDD + col] = f2bf(t);
        }
      }
    }
  }
  __syncthreads();
}

// One block (1024 threads = 16 waves) per batch row. Level-scheduled tree RNN.
__global__ __launch_bounds__(1024) void tree_rnn(
    const int* __restrict__ left, const int* __restrict__ right,
    const int* __restrict__ values,
    const float* __restrict__ W_ih, const float* __restrict__ b_ih,
    const float* __restrict__ W_o,  const float* __restrict__ b_o,
    const unsigned short* __restrict__ Wp,
    unsigned short* __restrict__ Hbuf, float* __restrict__ out)
{
  __shared__ unsigned short A_s[32][HIDD + 8];   // 33280 B, +8 pad vs bank conflicts
  __shared__ int li_s[NNODE], ri_s[NNODE], val_s[NNODE];
  __shared__ int lvl_s[NNODE], ord_s[NNODE];
  __shared__ int cnt_s[NNODE], cnt2_s[NNODE];
  __shared__ int offs_s[NNODE + 1];
  __shared__ int chg_s, lmax_s;
  __shared__ float hroot_s[HIDD];
  __shared__ float red_s[OUTD][16];
  __shared__ float logit_s[64];

  const int b    = blockIdx.x;
  const int tid  = threadIdx.x;                  // 0..1023
  const int lane = tid & 63;
  const int w    = tid >> 6;                     // 0..15
  unsigned short* Hb = Hbuf + (size_t)b * (NNODE + 1) * HIDD;

  // ---- load tree + init (ws is poisoned 0xAA: must zero sentinel row) ----
  if (tid < NNODE) {
    li_s[tid]  = left  [b * NNODE + tid];
    ri_s[tid]  = right [b * NNODE + tid];
    val_s[tid] = values[b * NNODE + tid];
    lvl_s[tid] = 0; cnt_s[tid] = 0; cnt2_s[tid] = 0;
    Hb[(size_t)NNODE * HIDD + tid] = 0;          // H[b][512][:] = 0 (null-child row)
  }
  if (tid == 0) lmax_s = 0;
  __syncthreads();

  // ---- level fixpoint: lvl[i] = 1 + max(lvl[children]), null -> -1 ----
  for (;;) {
    if (tid == 0) chg_s = 0;
    __syncthreads();
    if (tid < NNODE) {
      int l = li_s[tid], r = ri_s[tid];
      int dl = (l >= 0) ? lvl_s[l] : -1;
      int dr = (r >= 0) ? lvl_s[r] : -1;
      int nl = 1 + (dl > dr ? dl : dr);
      if (nl > lvl_s[tid]) { lvl_s[tid] = nl; chg_s = 1; }   // monotone -> converges
    }
    __syncthreads();
    if (!chg_s) break;
  }

  // ---- bucket nodes by level (counting sort in LDS) ----
  int myl = 0;
  if (tid < NNODE) {
    myl = lvl_s[tid];
    int ml = myl;
    #pragma unroll
    for (int m = 1; m < 64; m <<= 1) ml = max(ml, __shfl_xor(ml, m, 64));
    if (lane == 0) atomicMax(&lmax_s, ml);
    atomicAdd(&cnt_s[myl], 1);
  }
  __syncthreads();
  const int Lmax = lmax_s;
  if (tid == 0) {
    int acc = 0;
    for (int L = 0; L <= Lmax; ++L) { offs_s[L] = acc; acc += cnt_s[L]; }
    offs_s[Lmax + 1] = acc;                      // == 512
  }
  __syncthreads();
  if (tid < NNODE) {
    int pos = offs_s[myl] + atomicAdd(&cnt2_s[myl], 1);
    ord_s[pos] = tid;
  }
  __syncthreads();

  const int m16  = lane & 15;
  const int quad = lane >> 4;

  // ---- level loop: per level, GEMM (Mcur x 512) @ Wh(512x512), tanh, scatter ----
  for (int L = 0; L <= Lmax; ++L) {
    const int start = offs_s[L], end = offs_s[L + 1];
    for (int m0 = start; m0 < end; m0 += 32) {
      const int Mcur = min(32, end - m0);
      if (Mcur > 16)
        chunk_body<2>(m0, Mcur, w, lane, m16, quad, tid, A_s,
                      ord_s, li_s, ri_s, val_s, Wp, W_ih, b_ih, Hb);
      else
        chunk_body<1>(m0, Mcur, w, lane, m16, quad, tid, A_s,
                      ord_s, li_s, ri_s, val_s, Wp, W_ih, b_ih, Hb);
    }
  }

  // ---- logits + log_softmax for this batch row ----
  if (tid < HIDD) hroot_s[tid] = bf2f(Hb[(size_t)(NNODE - 1) * HIDD + tid]);
  __syncthreads();
  {
    const int j = tid >> 4, part = tid & 15;     // 16 threads per output
    if (j < OUTD) {
      float p = 0.f;
      const int k0 = part * 32;
      for (int k = k0; k < k0 + 32; ++k)
        p += hroot_s[k] * W_o[(size_t)k * OUTD + j];
      red_s[j][part] = p;
    }
  }
  __syncthreads();
  if (tid < OUTD) {
    float s = b_o[tid];
    #pragma unroll
    for (int p = 0; p < 16; ++p) s += red_s[tid][p];
    logit_s[tid] = s;
  }
  __syncthreads();
  if (w == 0) {
    float x = (lane < OUTD) ? logit_s[lane] : -1e30f;
    float mx = x;
    #pragma unroll
    for (int m = 1; m < 64; m <<= 1) mx = fmaxf(mx, __shfl_xor(mx, m, 64));
    float ex = (lane < OUTD) ? __expf(x - mx) : 0.f;
    float sm = ex;
    #pragma unroll
    for (int m = 1; m < 64; m <<= 1) sm += __shfl_xor(sm, m, 64);
    float ls = logf(sm);
    if (lane < OUTD) out[b * OUTD + lane] = x - mx - ls;
  }
}

extern "C" void kernel_launch(void* const* d_in, const int* in_sizes, int n_in,
                              void* d_out, int out_size, void* d_ws, size_t ws_size,
                              hipStream_t stream) {
  const int*   left   = (const int*)  d_in[0];
  const int*   right  = (const int*)  d_in[1];
  const int*   values = (const int*)  d_in[2];
  const float* W_ih   = (const float*)d_in[3];
  const float* b_ih   = (const float*)d_in[4];
  const float* W_o    = (const float*)d_in[5];
  const float* b_o    = (const float*)d_in[6];
  float* out = (float*)d_out;

  // workspace layout: [0, 512KB) packed Wh bf16; then H: 256 x 513 x 512 bf16 (~134.5 MB)
  unsigned short* Wp   = (unsigned short*)d_ws;
  unsigned short* Hbuf = (unsigned short*)((char*)d_ws + 512 * 1024);

  pack_wh<<<1024, 256, 0, stream>>>(W_ih, Wp);
  tree_rnn<<<BATCH, 1024, 0, stream>>>(left, right, values, W_ih, b_ih, W_o, b_o,
                                       Wp, Hbuf, out);
}